// Round 4
// baseline (826.280 us; speedup 1.0000x reference)
//
#include <hip/hip_runtime.h>
#include <hip/hip_bf16.h>
#include <cstdint>

// EdgeFrontierPolicy: E=400000, G=64, H=256.
// Wave-independent design: W1^T resident in LDS (128KB, frag-packed, ln1_g
// folded), each wave owns a 32-edge tile end-to-end with ZERO barriers after
// the prologue. GEMM1 computed transposed (h1^T = W1g^T x zln^T) so LN output
// feeds MFMA directly from registers; h1^T -> h1 A-frags via ds_bpermute;
// GEMM2 B-frags streamed from L2 with register double-buffer.

typedef __bf16 bf16x8 __attribute__((ext_vector_type(8)));
typedef float  f32x4  __attribute__((ext_vector_type(4)));

typedef __attribute__((address_space(1))) const char gas_char;
typedef __attribute__((address_space(3))) char las_char;

__device__ __forceinline__ float gelu_f(float x) {
  float x2 = x * x;
  float t1 = __builtin_fmaf(0.1029444f, x2, 2.3022078f);
  float a  = x * t1;
  float e;
  asm("v_exp_f32 %0, %1" : "=v"(e) : "v"(a));
  float r;
  asm("v_rcp_f32 %0, %1" : "=v"(r) : "v"(e + 1.0f));
  return x - x * r;   // x*sigmoid(1.59577*(x+0.044715x^3)*ln2-scaled) ~ gelu
}

__device__ __forceinline__ bf16x8 as_frag(uint4 u) {
  union { uint4 u; bf16x8 f; } c; c.u = u; return c.f;
}
__device__ __forceinline__ unsigned pk2(float a, float b) {
  union { __bf16 h[2]; unsigned u; } c;
  c.h[0] = (__bf16)a; c.h[1] = (__bf16)b; return c.u;
}

// ---------------------------------------------------------------------------
// Pack W1 (ln1_g folded) / W2 into MFMA frag order, bf16.
// out[((kt*16+nt)*64 + l)*8 + i] = W[32kt + 8*(l>>4)+i][16nt + (l&15)]
// (B-frag pack of W == A-frag pack of W^T: reused for both GEMMs.)
__global__ void prep_pack(const float* __restrict__ W1, const float* __restrict__ W2,
                          const float* __restrict__ ln1g,
                          __bf16* __restrict__ W1p, __bf16* __restrict__ W2p) {
  int gid = blockIdx.x * blockDim.x + threadIdx.x;   // 16384 threads
  int m  = gid >> 13;
  int b  = (gid >> 6) & 127;
  int l  = gid & 63;
  int kt = b >> 4, nt = b & 15;
  int k0 = kt * 32 + ((l >> 4) << 3);
  int n  = nt * 16 + (l & 15);
  const float* W = m ? W2 : W1;
  bf16x8 v;
#pragma unroll
  for (int i = 0; i < 8; ++i) {
    int k = k0 + i;
    float wv = W[k * 256 + n];
    if (!m) wv *= ln1g[k];
    v[i] = (__bf16)wv;
  }
  __bf16* dst = m ? W2p : W1p;
  *(bf16x8*)(dst + (size_t)(b * 64 + l) * 8) = v;
}

// C0/GW6/GW7 + mask dtype detect.
__global__ void prep_vec(const float* __restrict__ W1, const float* __restrict__ ln1g,
                         const float* __restrict__ ln1b, const float* __restrict__ b1,
                         const unsigned* __restrict__ smask_words,
                         float* __restrict__ C0, float* __restrict__ GW6,
                         float* __restrict__ GW7, int* __restrict__ maskIsByte) {
  __shared__ float red[4][256];
  const int n = threadIdx.x & 255, c = threadIdx.x >> 8;
  const int k0 = c * 64, k1 = (c == 3) ? 258 : k0 + 64;
  float s = 0.f;
#pragma unroll 4
  for (int k = k0; k < k1; ++k) s += ln1b[k] * W1[k * 256 + n];
  red[c][n] = s;
  __syncthreads();
  if (c == 0) {
    C0[n]  = b1[n] + red[0][n] + red[1][n] + red[2][n] + red[3][n];
    GW6[n] = ln1g[256] * W1[256 * 256 + n];
    GW7[n] = ln1g[257] * W1[257 * 256 + n];
  }
  if (threadIdx.x == 0) {
    int big = 0;
    for (int i = 0; i < 64; ++i) { if (smask_words[i] > 1u) big = 1; }
    *maskIsByte = big;
  }
}

// ---------------------------------------------------------------------------
__global__ __launch_bounds__(512, 2) void edge_kernel(
    const float* __restrict__ tok, const int* __restrict__ ebatch,
    const unsigned char* __restrict__ smaskB,
    const int* __restrict__ eheads, const int* __restrict__ etails,
    const int* __restrict__ curtail,
    const __bf16* __restrict__ W1p, const __bf16* __restrict__ W2p,
    const float* __restrict__ C0v, const float* __restrict__ GW6v,
    const float* __restrict__ GW7v, const float* __restrict__ b2v,
    const float* __restrict__ selwv, const float* __restrict__ selbv,
    const int* __restrict__ maskFlag,
    float* __restrict__ outLogits, float* __restrict__ pooledAcc,
    float* __restrict__ cnts, int E) {
  __shared__ __align__(16) char Wlds[131072];     // W1^T frag-packed, resident
  __shared__ float sC0[256], sW6[256], sW7[256], sSelw[256], sB2[256];

  const int t  = threadIdx.x;
  const int w  = t >> 6, l = t & 63;
  const int lo = l & 15, g = l >> 4;

  // ---- prologue: stage W1^T -> LDS (wave-linear), small vectors -> LDS ----
  {
    const char* Wsrc = (const char*)W1p;
    unsigned woff = __builtin_amdgcn_readfirstlane((unsigned)w * 16384u);
#pragma unroll
    for (int it = 0; it < 16; ++it)
      __builtin_amdgcn_global_load_lds((gas_char*)(Wsrc + woff + it * 1024 + l * 16),
                                       (las_char*)(Wlds + woff + it * 1024), 16, 0, 0);
  }
  if (t < 256) {
    sC0[t] = C0v[t]; sW6[t] = GW6v[t]; sW7[t] = GW7v[t];
    sSelw[t] = selwv[t]; sB2[t] = b2v[t];
  }
  const int   mb    = *maskFlag;
  const float selbr = selbv[0];
  __syncthreads();   // drains global_load_lds; LAST barrier in the kernel

  const int totalTiles = E >> 5;                 // 32 edges per tile
  const int nWaves = gridDim.x * 8;
  const char* W2c = (const char*)W2p;

  for (int tile = blockIdx.x * 8 + w; tile < totalTiles; tile += nWaves) {
    const int base = tile << 5;

    // ---- flags (lanes 0..31, one edge each) ----
    float candf = 0.f, frontf = 0.f; int gid = 0;
    if (l < 32) {
      int ge = base + l;
      gid = ebatch[ge];
      int mv = mb ? (int)smaskB[ge] : ((const int*)smaskB)[ge];
      int cand = (mv == 0);
      int cur  = curtail[gid];
      int fr   = cand && ((eheads[ge] == cur) || (etails[ge] == cur));
      candf = (float)cand; frontf = (float)fr;
    }
    const int g0s = __shfl(gid, 0);
    const bool uniform =
        (__ballot((l < 32) ? (gid == g0s) : 1) == ~0ull);
    {  // counts: boundary lanes add run lengths
      int gp = __shfl(gid, (l == 0) ? 0 : l - 1);
      bool isb = (l < 32) && (l == 0 || gid != gp);
      unsigned long long bm = __ballot(isb);
      if (isb) {
        unsigned long long m2 = bm >> (l + 1);
        int run = m2 ? (int)__ffsll((long long)m2) : (32 - l);
        atomicAdd(&cnts[gid], (float)run);
      }
    }
    // flags to row owners (row a = lo, row b = 16+lo)
    const float ca = __shfl(candf, lo),      fa = __shfl(frontf, lo);
    const float cb = __shfl(candf, 16 + lo), fb = __shfl(frontf, 16 + lo);

    // ---- LayerNorm, fully in-register; produce zln B-frags per row ----
    uint4 zlnA[8], zlnB[8];
    float za0a, za1a, za0b, za1b;
#pragma unroll
    for (int rr = 0; rr < 2; ++rr) {
      const int   edge = base + rr * 16 + lo;
      const float aux0 = rr ? cb : ca, aux1 = rr ? fb : fa;
      const float* rp = tok + (size_t)edge * 256 + (g << 3);
      float4 v[16];
#pragma unroll
      for (int kt = 0; kt < 8; ++kt) {
        v[2 * kt]     = *(const float4*)(rp + kt * 32);
        v[2 * kt + 1] = *(const float4*)(rp + kt * 32 + 4);
      }
      float s = 0.f, s2 = 0.f;
#pragma unroll
      for (int j = 0; j < 16; ++j) {
        s  += v[j].x + v[j].y + v[j].z + v[j].w;
        s2 += v[j].x * v[j].x + v[j].y * v[j].y + v[j].z * v[j].z + v[j].w * v[j].w;
      }
      s  += __shfl_xor(s, 16);  s  += __shfl_xor(s, 32);
      s2 += __shfl_xor(s2, 16); s2 += __shfl_xor(s2, 32);
      s += aux0 + aux1; s2 += aux0 + aux1;          // 0/1 flags: x == x^2
      const float mean = s * (1.0f / 258.0f);
      const float var  = s2 * (1.0f / 258.0f) - mean * mean;
      const float rstd = rsqrtf(var + 1e-5f);
      const float nm   = -mean * rstd;
      uint4* zf = rr ? zlnB : zlnA;
#pragma unroll
      for (int kt = 0; kt < 8; ++kt) {
        union { __bf16 h[8]; uint4 u; } cv;
#pragma unroll
        for (int q = 0; q < 4; ++q) {
          float x0 = (q < 2) ? ((q & 1) ? v[2*kt].z : v[2*kt].x)
                             : ((q & 1) ? v[2*kt+1].z : v[2*kt+1].x);
          float x1 = (q < 2) ? ((q & 1) ? v[2*kt].w : v[2*kt].y)
                             : ((q & 1) ? v[2*kt+1].w : v[2*kt+1].y);
          cv.h[2*q]   = (__bf16)__builtin_fmaf(x0, rstd, nm);
          cv.h[2*q+1] = (__bf16)__builtin_fmaf(x1, rstd, nm);
        }
        zf[kt] = cv.u;
      }
      if (rr) { za0b = __builtin_fmaf(aux0, rstd, nm); za1b = __builtin_fmaf(aux1, rstd, nm); }
      else    { za0a = __builtin_fmaf(aux0, rstd, nm); za1a = __builtin_fmaf(aux1, rstd, nm); }
    }

    // ---- GEMM1 (transposed): h1^T[n][m], j-halves; repack to h1 A-frags ----
    uint4 h1f[2][8];   // [mt][kt2]
#pragma unroll
    for (int half = 0; half < 2; ++half) {
      f32x4 acc[8][2];   // [jl][mt]
#pragma unroll
      for (int jl = 0; jl < 8; ++jl) {
        const int j = half * 8 + jl;
        f32x4 c0 = *(const f32x4*)&sC0[j * 16 + g * 4];
        f32x4 w6 = *(const f32x4*)&sW6[j * 16 + g * 4];
        f32x4 w7 = *(const f32x4*)&sW7[j * 16 + g * 4];
#pragma unroll
        for (int i = 0; i < 4; ++i) {
          acc[jl][0][i] = c0[i] + za0a * w6[i] + za1a * w7[i];
          acc[jl][1][i] = c0[i] + za0b * w6[i] + za1b * w7[i];
        }
      }
#pragma unroll
      for (int kt = 0; kt < 8; ++kt) {
        bf16x8 afr[8];
#pragma unroll
        for (int jl = 0; jl < 8; ++jl)
          afr[jl] = as_frag(*(const uint4*)(Wlds + (size_t)(kt * 16 + half * 8 + jl) * 1024 + l * 16));
        bf16x8 bA = as_frag(zlnA[kt]), bB = as_frag(zlnB[kt]);
#pragma unroll
        for (int jl = 0; jl < 8; ++jl) {
          acc[jl][0] = __builtin_amdgcn_mfma_f32_16x16x32_bf16(afr[jl], bA, acc[jl][0], 0, 0, 0);
          acc[jl][1] = __builtin_amdgcn_mfma_f32_16x16x32_bf16(afr[jl], bB, acc[jl][1], 0, 0, 0);
        }
      }
      // gelu + pack pairs: pk[mt][jl][p] = bf16(gelu(acc[2p]), gelu(acc[2p+1]))
      unsigned pk[2][8][2];
#pragma unroll
      for (int mt = 0; mt < 2; ++mt)
#pragma unroll
        for (int jl = 0; jl < 8; ++jl) {
          pk[mt][jl][0] = pk2(gelu_f(acc[jl][mt][0]), gelu_f(acc[jl][mt][1]));
          pk[mt][jl][1] = pk2(gelu_f(acc[jl][mt][2]), gelu_f(acc[jl][mt][3]));
        }
      // shuffle h1^T -> h1 A-frags (kt2 in [half*4, half*4+4))
      // dst dword t of frag(mt,kt2): value pk[mt][2*k2l + (g>>1)][t&1]
      //   from lane 16*(2*(g&1) + (t>>1)) + lo
#pragma unroll
      for (int mt = 0; mt < 2; ++mt)
#pragma unroll
        for (int k2l = 0; k2l < 4; ++k2l) {
          unsigned dw[4];
#pragma unroll
          for (int tt = 0; tt < 4; ++tt) {
            int src = 16 * (2 * (g & 1) + (tt >> 1)) + lo;
            unsigned dE = __shfl(pk[mt][2 * k2l][tt & 1], src);
            unsigned dO = __shfl(pk[mt][2 * k2l + 1][tt & 1], src);
            dw[tt] = (g >= 2) ? dO : dE;
          }
          h1f[mt][half * 4 + k2l] = make_uint4(dw[0], dw[1], dw[2], dw[3]);
        }
    }

    // ---- GEMM2: h2 = h1 @ W2 (B-frags from L2, reg double-buffer), cf-halves ----
    float plog[2][4];
#pragma unroll
    for (int mt = 0; mt < 2; ++mt)
#pragma unroll
      for (int i = 0; i < 4; ++i) plog[mt][i] = 0.f;

#pragma unroll
    for (int ch = 0; ch < 2; ++ch) {
      f32x4 acc2[8][2];  // [c8][mt]
#pragma unroll
      for (int c8 = 0; c8 < 8; ++c8) {
        float bb = sB2[(ch * 8 + c8) * 16 + lo];
#pragma unroll
        for (int mt = 0; mt < 2; ++mt)
#pragma unroll
          for (int i = 0; i < 4; ++i) acc2[c8][mt][i] = bb;
      }
      const char* wbase = W2c + (size_t)ch * 8192 + (size_t)l * 16;
      uint4 b0[8], b1[8];
#pragma unroll
      for (int c8 = 0; c8 < 8; ++c8) b0[c8] = *(const uint4*)(wbase + c8 * 1024);
#pragma unroll
      for (int kt2 = 0; kt2 < 8; ++kt2) {
        if (kt2 < 7) {
          if (kt2 & 1) {
#pragma unroll
            for (int c8 = 0; c8 < 8; ++c8)
              b0[c8] = *(const uint4*)(wbase + (size_t)(kt2 + 1) * 16384 + c8 * 1024);
          } else {
#pragma unroll
            for (int c8 = 0; c8 < 8; ++c8)
              b1[c8] = *(const uint4*)(wbase + (size_t)(kt2 + 1) * 16384 + c8 * 1024);
          }
        }
        bf16x8 a0 = as_frag(h1f[0][kt2]), a1 = as_frag(h1f[1][kt2]);
#pragma unroll
        for (int c8 = 0; c8 < 8; ++c8) {
          bf16x8 bf = as_frag((kt2 & 1) ? b1[c8] : b0[c8]);
          acc2[c8][0] = __builtin_amdgcn_mfma_f32_16x16x32_bf16(a0, bf, acc2[c8][0], 0, 0, 0);
          acc2[c8][1] = __builtin_amdgcn_mfma_f32_16x16x32_bf16(a1, bf, acc2[c8][1], 0, 0, 0);
        }
      }
      // gelu + logits partial + pooled for this cf-half
#pragma unroll
      for (int c8 = 0; c8 < 8; ++c8) {
        float wv = sSelw[(ch * 8 + c8) * 16 + lo];
#pragma unroll
        for (int mt = 0; mt < 2; ++mt)
#pragma unroll
          for (int i = 0; i < 4; ++i) {
            acc2[c8][mt][i] = gelu_f(acc2[c8][mt][i]);
            plog[mt][i] += acc2[c8][mt][i] * wv;
          }
      }
      if (uniform) {
#pragma unroll
        for (int c8 = 0; c8 < 8; ++c8) {
          float pv = 0.f;
#pragma unroll
          for (int mt = 0; mt < 2; ++mt)
#pragma unroll
            for (int i = 0; i < 4; ++i) pv += acc2[c8][mt][i];
          pv += __shfl_xor(pv, 16);
          pv += __shfl_xor(pv, 32);
          if (l < 16) atomicAdd(&pooledAcc[g0s * 256 + (ch * 8 + c8) * 16 + l], pv);
        }
      } else {
        int gm[2][4];
#pragma unroll
        for (int mt = 0; mt < 2; ++mt)
#pragma unroll
          for (int i = 0; i < 4; ++i) gm[mt][i] = __shfl(gid, 16 * mt + 4 * g + i);
#pragma unroll
        for (int c8 = 0; c8 < 8; ++c8)
#pragma unroll
          for (int mt = 0; mt < 2; ++mt)
#pragma unroll
            for (int i = 0; i < 4; ++i)
              atomicAdd(&pooledAcc[gm[mt][i] * 256 + (ch * 8 + c8) * 16 + lo],
                        acc2[c8][mt][i]);
      }
    }

    // ---- logits: reduce over n2 lanes, add bonus, write ----
    float fm[2][4];
#pragma unroll
    for (int mt = 0; mt < 2; ++mt)
#pragma unroll
      for (int i = 0; i < 4; ++i) fm[mt][i] = __shfl(frontf, 16 * mt + 4 * g + i);
#pragma unroll
    for (int mt = 0; mt < 2; ++mt)
#pragma unroll
      for (int i = 0; i < 4; ++i) {
        float p = plog[mt][i];
        p += __shfl_xor(p, 1); p += __shfl_xor(p, 2);
        p += __shfl_xor(p, 4); p += __shfl_xor(p, 8);
        if (lo == 0)
          outLogits[base + 16 * mt + 4 * g + i] = p + selbr + 0.5f * fm[mt][i];
      }
  }
}

// ---------------------------------------------------------------------------
__global__ __launch_bounds__(256) void stop_kernel(
    const float* __restrict__ pooledAcc, const float* __restrict__ cnts,
    const float* __restrict__ qtok,
    const float* __restrict__ ln2g, const float* __restrict__ ln2b,
    const float* __restrict__ sW1, const float* __restrict__ sb1,
    const float* __restrict__ sW2, const float* __restrict__ sb2,
    float* __restrict__ outStop, float* __restrict__ outPooled) {
  __shared__ float sIn[512], sLn[512], sRed[8];
  const int t = threadIdx.x, g = blockIdx.x;
  const int w = t >> 6, l = t & 63;
  float c = fmaxf(cnts[g], 1.0f);
  float p = pooledAcc[g * 256 + t] / c;
  outPooled[g * 256 + t] = p;
  sIn[t] = p;
  sIn[256 + t] = qtok[g * 256 + t];
  __syncthreads();
  float a = sIn[t], b = sIn[256 + t];
  float s = a + b, s2 = a * a + b * b;
#pragma unroll
  for (int m = 1; m < 64; m <<= 1) { s += __shfl_xor(s, m); s2 += __shfl_xor(s2, m); }
  if (l == 0) { sRed[w] = s; sRed[4 + w] = s2; }
  __syncthreads();
  s  = sRed[0] + sRed[1] + sRed[2] + sRed[3];
  s2 = sRed[4] + sRed[5] + sRed[6] + sRed[7];
  const float mean = s * (1.0f / 512.0f);
  const float var  = s2 * (1.0f / 512.0f) - mean * mean;
  const float rstd = rsqrtf(var + 1e-5f);
  sLn[t]       = (a - mean) * rstd * ln2g[t] + ln2b[t];
  sLn[256 + t] = (b - mean) * rstd * ln2g[256 + t] + ln2b[256 + t];
  __syncthreads();
  float accv = sb1[t];
#pragma unroll 8
  for (int k = 0; k < 512; ++k) accv += sLn[k] * sW1[k * 256 + t];
  float u = gelu_f(accv);
  float part = u * sW2[t];
#pragma unroll
  for (int m = 1; m < 64; m <<= 1) part += __shfl_xor(part, m);
  if (l == 0) sRed[w] = part;
  __syncthreads();
  if (t == 0) outStop[g] = sRed[0] + sRed[1] + sRed[2] + sRed[3] + sb2[0];
}

// ---------------------------------------------------------------------------
extern "C" void kernel_launch(void* const* d_in, const int* in_sizes, int n_in,
                              void* d_out, int out_size, void* d_ws, size_t ws_size,
                              hipStream_t stream) {
  const float* tok   = (const float*)d_in[0];
  const float* qtok  = (const float*)d_in[1];
  const int* ebatch  = (const int*)d_in[2];
  const void* smask  = d_in[3];
  const int* eheads  = (const int*)d_in[4];
  const int* etails  = (const int*)d_in[5];
  const int* curtail = (const int*)d_in[6];
  const float* ln1g  = (const float*)d_in[7];
  const float* ln1b  = (const float*)d_in[8];
  const float* W1    = (const float*)d_in[9];
  const float* b1    = (const float*)d_in[10];
  const float* W2    = (const float*)d_in[11];
  const float* b2    = (const float*)d_in[12];
  const float* selw  = (const float*)d_in[13];
  const float* selb  = (const float*)d_in[14];
  const float* ln2g  = (const float*)d_in[15];
  const float* ln2b  = (const float*)d_in[16];
  const float* sW1   = (const float*)d_in[17];
  const float* sb1   = (const float*)d_in[18];
  const float* sW2   = (const float*)d_in[19];
  const float* sb2   = (const float*)d_in[20];

  const int E = in_sizes[2];            // 400000 (divisible by 32)
  const int G = in_sizes[1] / 256;      // 64

  char* ws = (char*)d_ws;
  __bf16* W1p   = (__bf16*)(ws);                 // 131072 B
  __bf16* W2p   = (__bf16*)(ws + 131072);        // 131072 B
  float*  C0    = (float*)(ws + 262144);
  float*  GW6   = (float*)(ws + 263168);
  float*  GW7   = (float*)(ws + 264192);
  float*  pooled= (float*)(ws + 265216);         // 65536 B
  float*  cnts  = (float*)(ws + 330752);         // 256 B
  int*    mflag = (int*)(ws + 331008);           // 4 B
  (void)ws_size; (void)n_in; (void)out_size;

  hipMemsetAsync(ws + 265216, 0, 65536 + 256, stream);  // pooled + counts

  prep_pack<<<64, 256, 0, stream>>>(W1, W2, ln1g, W1p, W2p);
  prep_vec<<<1, 1024, 0, stream>>>(W1, ln1g, ln1b, b1, (const unsigned*)smask,
                                   C0, GW6, GW7, mflag);
  edge_kernel<<<256, 512, 0, stream>>>(
      tok, ebatch, (const unsigned char*)smask, eheads, etails, curtail,
      W1p, W2p, C0, GW6, GW7, b2, selw, selb, mflag,
      (float*)d_out, pooled, cnts, E);
  stop_kernel<<<G, 256, 0, stream>>>(pooled, cnts, qtok, ln2g, ln2b,
                                     sW1, sb1, sW2, sb2,
                                     (float*)d_out + E, (float*)d_out + E + G);
}